// Round 4
// baseline (1037.347 us; speedup 1.0000x reference)
//
#include <hip/hip_runtime.h>
#include <stdint.h>
#include <stddef.h>

typedef __attribute__((ext_vector_type(8))) short short8;
typedef __attribute__((ext_vector_type(4))) float float4v;

#define T_SEQ 2048
#define D_MODEL 1024
#define NH 16
#define HD 64

static __device__ __forceinline__ unsigned short f2bf(float f) {
  unsigned u = __builtin_bit_cast(unsigned, f);
  u += 0x7fffu + ((u >> 16) & 1u);
  return (unsigned short)(u >> 16);
}
static __device__ __forceinline__ float bf2f(unsigned short h) {
  unsigned u = ((unsigned)h) << 16;
  return __builtin_bit_cast(float, u);
}
static __device__ __forceinline__ float4v mfma16(short8 a, short8 b, float4v c) {
  return __builtin_amdgcn_mfma_f32_16x16x32_bf16(a, b, c, 0, 0, 0);
}
// fp32 -> 3 bf16 terms (sum reproduces f to ~2^-27 rel)
static __device__ __forceinline__ void split3(float f, unsigned short& h0,
                                              unsigned short& h1, unsigned short& h2) {
  h0 = f2bf(f);
  float r1 = f - bf2f(h0);
  h1 = f2bf(r1);
  float r2 = r1 - bf2f(h1);
  h2 = f2bf(r2);
}
// fp32 -> 2 bf16 terms (~2^-18 rel)
static __device__ __forceinline__ void split2(float f, unsigned short& h0, unsigned short& h1) {
  h0 = f2bf(f);
  h1 = f2bf(f - bf2f(h0));
}

// ---------------- eta tables ----------------
__global__ void eta_kernel(const float* theta, float* E, float* Einv) {
  int i = blockIdx.x * blockDim.x + threadIdx.x;
  if (i >= T_SEQ) return;
  float th = theta[0];
  float h = log1pf(expf(th));            // softplus
  float t = 1.0f + h * (float)i;         // T0 = 1
  float eta = 3.0f * logf(t);            // C_LOG = 3
  eta = fminf(fmaxf(eta, -50.0f), 50.0f);
  E[i] = expf(eta);
  Einv[i] = expf(-eta);
}

// ---------------- LayerNorm (fp32 in) -> 3-way split y ----------------
__global__ __launch_bounds__(256) void ln_kernel(const float* x, const float* wgt,
                          unsigned short* y0, unsigned short* y1, unsigned short* y2) {
  int row = blockIdx.x;
  int tid = threadIdx.x;
  const float* xr = x + (size_t)row * D_MODEL;
  float v[4];
  float sum = 0.f, ssq = 0.f;
  for (int it = 0; it < 4; ++it) {
    float f = xr[tid + 256 * it];
    v[it] = f;
    sum += f; ssq += f * f;
  }
  for (int off = 32; off >= 1; off >>= 1) {
    sum += __shfl_xor(sum, off, 64);
    ssq += __shfl_xor(ssq, off, 64);
  }
  __shared__ float rs[4], rq[4];
  int w = tid >> 6;
  if ((tid & 63) == 0) { rs[w] = sum; rq[w] = ssq; }
  __syncthreads();
  sum = rs[0] + rs[1] + rs[2] + rs[3];
  ssq = rq[0] + rq[1] + rq[2] + rq[3];
  float mu = sum * (1.0f / D_MODEL);
  float var = ssq * (1.0f / D_MODEL) - mu * mu;
  float rstd = rsqrtf(var + 1e-5f);
  for (int it = 0; it < 4; ++it) {
    int d = tid + 256 * it;
    float y = (v[it] - mu) * rstd * wgt[d];
    unsigned short h0, h1, h2;
    split3(y, h0, h1, h2);
    size_t o = (size_t)row * D_MODEL + d;
    y0[o] = h0; y1[o] = h1; y2[o] = h2;
  }
}

// ---------------- attn_w (fp32) -> split3; W2 only for rows < 2048 (Q,K) ----------------
__global__ __launch_bounds__(256) void conv_w3(const float* src, unsigned short* W0,
                                               unsigned short* W1, unsigned short* W2) {
  size_t base = ((size_t)blockIdx.x * 256 + threadIdx.x) * 8;
  int row = (int)(base >> 10);
  short8 a, b, c;
  for (int j = 0; j < 8; ++j) {
    unsigned short h0, h1, h2;
    split3(src[base + j], h0, h1, h2);
    a[j] = (short)h0; b[j] = (short)h1; c[j] = (short)h2;
  }
  *(short8*)(W0 + base) = a;
  *(short8*)(W1 + base) = b;
  if (row < 2048) *(short8*)(W2 + base) = c;
}

// ---------------- proj_w (fp32) -> split2 ----------------
__global__ __launch_bounds__(256) void conv_pw(const float* src, unsigned short* P0,
                                               unsigned short* P1) {
  size_t base = ((size_t)blockIdx.x * 256 + threadIdx.x) * 8;
  short8 a, b;
  for (int j = 0; j < 8; ++j) {
    unsigned short h0, h1;
    split2(src[base + j], h0, h1);
    a[j] = (short)h0; b[j] = (short)h1;
  }
  *(short8*)(P0 + base) = a;
  *(short8*)(P1 + base) = b;
}

// ---------------- Q,K GEMM: fp32-grade via 6-term split MFMA ----------------
// Q region written fp32; K region written pre-split3 bf16 (K0,K1,K2).
__global__ __launch_bounds__(256) void qkv_qk(
    const unsigned short* y0, const unsigned short* y1, const unsigned short* y2,
    const unsigned short* W0, const unsigned short* W1, const unsigned short* W2,
    float* Qf, unsigned short* K0, unsigned short* K1, unsigned short* K2) {
  int tid = threadIdx.x;
  int w = tid >> 6, lane = tid & 63, q4 = lane >> 4, ln = lane & 15;
  int n0 = blockIdx.x * 64;          // 0..2047
  int m0 = blockIdx.y * 128;
  float4v zero = {0.f, 0.f, 0.f, 0.f};
  float4v acc[2][4];
  for (int mt = 0; mt < 2; ++mt)
    for (int c = 0; c < 4; ++c) acc[mt][c] = zero;

  for (int k0 = 0; k0 < D_MODEL; k0 += 32) {
    short8 a0[2], a1[2], a2[2], b0[4], b1[4], b2[4];
    for (int mt = 0; mt < 2; ++mt) {
      size_t off = (size_t)(m0 + w * 32 + mt * 16 + ln) * D_MODEL + k0 + q4 * 8;
      a0[mt] = *(const short8*)(y0 + off);
      a1[mt] = *(const short8*)(y1 + off);
      a2[mt] = *(const short8*)(y2 + off);
    }
    for (int c = 0; c < 4; ++c) {
      size_t off = (size_t)(n0 + c * 16 + ln) * D_MODEL + k0 + q4 * 8;
      b0[c] = *(const short8*)(W0 + off);
      b1[c] = *(const short8*)(W1 + off);
      b2[c] = *(const short8*)(W2 + off);
    }
    for (int mt = 0; mt < 2; ++mt)
      for (int c = 0; c < 4; ++c) {
        acc[mt][c] = mfma16(a0[mt], b0[c], acc[mt][c]);
        acc[mt][c] = mfma16(a1[mt], b0[c], acc[mt][c]);
        acc[mt][c] = mfma16(a0[mt], b1[c], acc[mt][c]);
        acc[mt][c] = mfma16(a1[mt], b1[c], acc[mt][c]);
        acc[mt][c] = mfma16(a0[mt], b2[c], acc[mt][c]);
        acc[mt][c] = mfma16(a2[mt], b0[c], acc[mt][c]);
      }
  }
  int region = n0 >> 10;            // 0=Q 1=K
  int h = (n0 & 1023) >> 6;
  for (int mt = 0; mt < 2; ++mt)
    for (int c = 0; c < 4; ++c)
      for (int r = 0; r < 4; ++r) {
        int gm = m0 + w * 32 + mt * 16 + q4 * 4 + r;
        int bi = gm >> 11, t = gm & 2047;
        int d = c * 16 + ln;
        size_t o = ((size_t)(bi * NH + h) * T_SEQ + t) * HD + d;
        float val = acc[mt][c][r];
        if (region == 0) {
          Qf[o] = val;
        } else {
          unsigned short h0, h1, h2;
          split3(val, h0, h1, h2);
          K0[o] = h0; K1[o] = h1; K2[o] = h2;
        }
      }
}

// ---------------- V GEMM (3-term, bf16-out, transposed [b,h,d,t]) ----------------
__global__ __launch_bounds__(256) void qkv_v(
    const unsigned short* y0, const unsigned short* y1,
    const unsigned short* W0, const unsigned short* W1, unsigned short* VbT) {
  int tid = threadIdx.x;
  int w = tid >> 6, lane = tid & 63, q4 = lane >> 4, ln = lane & 15;
  int n0 = 2048 + blockIdx.x * 64;   // V region rows of attn_w
  int m0 = blockIdx.y * 128;
  float4v zero = {0.f, 0.f, 0.f, 0.f};
  float4v acc[2][4];
  for (int mt = 0; mt < 2; ++mt)
    for (int c = 0; c < 4; ++c) acc[mt][c] = zero;

  for (int k0 = 0; k0 < D_MODEL; k0 += 32) {
    short8 a0[2], a1[2], b0[4], b1[4];
    for (int mt = 0; mt < 2; ++mt) {
      size_t off = (size_t)(m0 + w * 32 + mt * 16 + ln) * D_MODEL + k0 + q4 * 8;
      a0[mt] = *(const short8*)(y0 + off);
      a1[mt] = *(const short8*)(y1 + off);
    }
    for (int c = 0; c < 4; ++c) {
      size_t off = (size_t)(n0 + c * 16 + ln) * D_MODEL + k0 + q4 * 8;
      b0[c] = *(const short8*)(W0 + off);
      b1[c] = *(const short8*)(W1 + off);
    }
    for (int mt = 0; mt < 2; ++mt)
      for (int c = 0; c < 4; ++c) {
        acc[mt][c] = mfma16(a0[mt], b0[c], acc[mt][c]);
        acc[mt][c] = mfma16(a1[mt], b0[c], acc[mt][c]);
        acc[mt][c] = mfma16(a0[mt], b1[c], acc[mt][c]);
      }
  }
  int h = (n0 & 1023) >> 6;
  for (int mt = 0; mt < 2; ++mt)
    for (int c = 0; c < 4; ++c) {
      int tb = m0 + w * 32 + mt * 16 + q4 * 4;   // 4 consecutive t
      int bi = tb >> 11, t = tb & 2047;
      int d = c * 16 + ln;
      unsigned short tmp[4];
      for (int r = 0; r < 4; ++r) tmp[r] = f2bf(acc[mt][c][r]);
      *(uint64_t*)(VbT + ((size_t)((bi * NH + h) * HD + d) * T_SEQ + t)) =
          *(const uint64_t*)tmp;
    }
}

// ---------------- fused causal attention (flash-style, fp32-grade S) ----------------
__global__ __launch_bounds__(256) void attn_kernel(
    const float* Qf, const unsigned short* K0, const unsigned short* K1,
    const unsigned short* K2, const unsigned short* VbT,
    const float* E, const float* Einv, unsigned short* Ob0, unsigned short* Ob1) {
  __shared__ unsigned short Plds[4][16][72];   // per-wave P tile, padded
  int tid = threadIdx.x;
  int w = tid >> 6, lane = tid & 63, q4 = lane >> 4, ln = lane & 15;
  int qt = gridDim.x - 1 - blockIdx.x;   // longest blocks first
  int bh = blockIdx.y;
  int q0 = qt * 64;
  int ibase = q0 + w * 16;
  const float* Qb = Qf + (size_t)bh * T_SEQ * HD;
  size_t kbase = (size_t)bh * T_SEQ * HD;
  const unsigned short* Vb = VbT + (size_t)bh * HD * T_SEQ;

  // Q fragments, 3-way split (once per block; K is pre-split in memory)
  short8 qa[2][3];
  {
    const float* qp = Qb + (size_t)(ibase + ln) * HD;
    for (int ks = 0; ks < 2; ++ks) {
      float f[8];
      *(float4v*)&f[0] = *(const float4v*)(qp + ks * 32 + q4 * 8);
      *(float4v*)&f[4] = *(const float4v*)(qp + ks * 32 + q4 * 8 + 4);
      for (int j = 0; j < 8; ++j) {
        unsigned short h0, h1, h2;
        split3(f[j], h0, h1, h2);
        qa[ks][0][j] = (short)h0; qa[ks][1][j] = (short)h1; qa[ks][2][j] = (short)h2;
      }
    }
  }
  float ei[4];
  for (int r = 0; r < 4; ++r) ei[r] = E[ibase + q4 * 4 + r] * 0.125f; // fold 1/sqrt(64)

  float m_r[4] = {-3e38f, -3e38f, -3e38f, -3e38f};
  float l_r[4] = {0.f, 0.f, 0.f, 0.f};
  float4v zero = {0.f, 0.f, 0.f, 0.f};
  float4v oacc[4];
  for (int c = 0; c < 4; ++c) oacc[c] = zero;

  for (int jt = 0; jt <= qt; ++jt) {
    int j0 = jt * 64;
    bool diag = (jt == qt);
    float p[4][4];   // [c][r]: logits, then probabilities
    for (int c = 0; c < 4; ++c) {
      int jrow = j0 + c * 16 + ln;
      size_t ko = kbase + (size_t)jrow * HD;
      float4v s = zero;
      for (int ks = 0; ks < 2; ++ks) {
        size_t off = ko + ks * 32 + q4 * 8;
        short8 k0v = *(const short8*)(K0 + off);
        short8 k1v = *(const short8*)(K1 + off);
        short8 k2v = *(const short8*)(K2 + off);
        // 6-term split product: fp32-grade S
        s = mfma16(qa[ks][0], k0v, s);
        s = mfma16(qa[ks][1], k0v, s);
        s = mfma16(qa[ks][0], k1v, s);
        s = mfma16(qa[ks][1], k1v, s);
        s = mfma16(qa[ks][0], k2v, s);
        s = mfma16(qa[ks][2], k0v, s);
      }
      float ein = Einv[jrow];
      for (int r = 0; r < 4; ++r) {
        float l = s[r] * ei[r] * ein;
        if (diag && jrow > ibase + q4 * 4 + r) l = -3e38f;   // causal mask
        p[c][r] = l;
      }
    }
    // online softmax (each row lives on the 16 lanes sharing q4)
    float alpha[4], mnew[4];
    for (int r = 0; r < 4; ++r) {
      float tm = fmaxf(fmaxf(p[0][r], p[1][r]), fmaxf(p[2][r], p[3][r]));
      for (int off = 8; off >= 1; off >>= 1) tm = fmaxf(tm, __shfl_xor(tm, off, 16));
      mnew[r] = fmaxf(m_r[r], tm);
      alpha[r] = expf(m_r[r] - mnew[r]);
      m_r[r] = mnew[r];
    }
    float rssum[4] = {0.f, 0.f, 0.f, 0.f};
    for (int c = 0; c < 4; ++c)
      for (int r = 0; r < 4; ++r) {
        float pv = expf(p[c][r] - mnew[r]);
        p[c][r] = pv;
        rssum[r] += pv;
      }
    for (int r = 0; r < 4; ++r) {
      for (int off = 8; off >= 1; off >>= 1) rssum[r] += __shfl_xor(rssum[r], off, 16);
      l_r[r] = l_r[r] * alpha[r] + rssum[r];
    }
    for (int c = 0; c < 4; ++c)
      for (int r = 0; r < 4; ++r) oacc[c][r] *= alpha[r];

    __syncthreads();   // prev iteration's P reads done before overwrite
    for (int c = 0; c < 4; ++c)
      for (int r = 0; r < 4; ++r)
        Plds[w][q4 * 4 + r][c * 16 + ln] = f2bf(p[c][r]);
    __syncthreads();   // writes visible before A-layout reads

    // P·V (V fragments directly from transposed global layout)
    for (int ks = 0; ks < 2; ++ks) {
      short8 pa = *(const short8*)&Plds[w][ln][ks * 32 + q4 * 8];
      for (int c = 0; c < 4; ++c) {
        short8 vb = *(const short8*)(Vb + (size_t)(c * 16 + ln) * T_SEQ + j0 + ks * 32 + q4 * 8);
        oacc[c] = mfma16(pa, vb, oacc[c]);
      }
    }
  }
  int b = bh >> 4, hh = bh & 15;
  for (int c = 0; c < 4; ++c)
    for (int r = 0; r < 4; ++r) {
      int i = ibase + q4 * 4 + r;
      float val = oacc[c][r] / l_r[r];
      unsigned short h0, h1;
      split2(val, h0, h1);
      size_t o = ((size_t)(b * T_SEQ + i)) * D_MODEL + hh * 64 + c * 16 + ln;
      Ob0[o] = h0; Ob1[o] = h1;
    }
}

// ---------------- output projection (3-term split, fp32 out) ----------------
__global__ __launch_bounds__(256) void proj_gemm(
    const unsigned short* A0, const unsigned short* A1,
    const unsigned short* P0, const unsigned short* P1, float* out) {
  int tid = threadIdx.x;
  int w = tid >> 6, lane = tid & 63, q4 = lane >> 4, ln = lane & 15;
  int n0 = blockIdx.x * 64;
  int m0 = blockIdx.y * 128;
  float4v zero = {0.f, 0.f, 0.f, 0.f};
  float4v acc[2][4];
  for (int mt = 0; mt < 2; ++mt)
    for (int c = 0; c < 4; ++c) acc[mt][c] = zero;

  for (int k0 = 0; k0 < D_MODEL; k0 += 32) {
    short8 a0[2], a1[2], b0[4], b1[4];
    for (int mt = 0; mt < 2; ++mt) {
      size_t off = (size_t)(m0 + w * 32 + mt * 16 + ln) * D_MODEL + k0 + q4 * 8;
      a0[mt] = *(const short8*)(A0 + off);
      a1[mt] = *(const short8*)(A1 + off);
    }
    for (int c = 0; c < 4; ++c) {
      size_t off = (size_t)(n0 + c * 16 + ln) * D_MODEL + k0 + q4 * 8;
      b0[c] = *(const short8*)(P0 + off);
      b1[c] = *(const short8*)(P1 + off);
    }
    for (int mt = 0; mt < 2; ++mt)
      for (int c = 0; c < 4; ++c) {
        acc[mt][c] = mfma16(a0[mt], b0[c], acc[mt][c]);
        acc[mt][c] = mfma16(a1[mt], b0[c], acc[mt][c]);
        acc[mt][c] = mfma16(a0[mt], b1[c], acc[mt][c]);
      }
  }
  for (int mt = 0; mt < 2; ++mt)
    for (int c = 0; c < 4; ++c)
      for (int r = 0; r < 4; ++r) {
        int gm = m0 + w * 32 + mt * 16 + q4 * 4 + r;
        out[(size_t)gm * D_MODEL + n0 + c * 16 + ln] = acc[mt][c][r];
      }
}

extern "C" void kernel_launch(void* const* d_in, const int* in_sizes, int n_in,
                              void* d_out, int out_size, void* d_ws, size_t ws_size,
                              hipStream_t stream) {
  const float* x      = (const float*)d_in[0];
  const float* ln_w   = (const float*)d_in[1];
  const float* attn_w = (const float*)d_in[2];
  const float* proj_w = (const float*)d_in[3];
  const float* theta  = (const float*)d_in[4];
  float* out = (float*)d_out;

  char* ws = (char*)d_ws;
  const size_t SZY  = (size_t)4096 * 1024 * 2;        // 8,388,608
  const size_t SZW  = (size_t)3072 * 1024 * 2;        // 6,291,456
  const size_t SZW2 = (size_t)2048 * 1024 * 2;        // 4,194,304
  const size_t SZQ  = (size_t)2 * 16 * 2048 * 64 * 4; // 16,777,216 (fp32)
  const size_t SZK  = (size_t)2 * 16 * 2048 * 64 * 2; //  8,388,608 (bf16)

  unsigned short* y0 = (unsigned short*)(ws);
  unsigned short* y1 = (unsigned short*)(ws + SZY);
  unsigned short* y2 = (unsigned short*)(ws + 2 * SZY);
  unsigned short* W0 = (unsigned short*)(ws + 3 * SZY);
  unsigned short* W1 = (unsigned short*)(ws + 3 * SZY + SZW);
  unsigned short* W2 = (unsigned short*)(ws + 3 * SZY + 2 * SZW);
  float* Qf          = (float*)(ws + 3 * SZY + 2 * SZW + SZW2);
  unsigned short* K0 = (unsigned short*)(ws + 3 * SZY + 2 * SZW + SZW2 + SZQ);
  unsigned short* K1 = (unsigned short*)(ws + 3 * SZY + 2 * SZW + SZW2 + SZQ + SZK);
  float* E           = (float*)(ws + 3 * SZY + 2 * SZW + SZW2 + SZQ + 2 * SZK);
  float* Einv        = E + T_SEQ;
  // aliases into dead regions (y dead after qkv_*, then reused):
  unsigned short* Ob0 = y0;
  unsigned short* Ob1 = y1;
  unsigned short* PW0 = y2;
  unsigned short* PW1 = y2 + (size_t)1024 * 1024;
  // d_out scratch (16.78 MB): VbT low half, K2 high half; both dead before proj writes
  unsigned short* VbT = (unsigned short*)d_out;
  unsigned short* K2  = (unsigned short*)((char*)d_out + SZK);

  size_t needed = 3 * SZY + 2 * SZW + SZW2 + SZQ + 2 * SZK + 2 * T_SEQ * 4;  // 75,513,856
  if (ws_size < needed) return;  // loud failure: output stays zero

  eta_kernel<<<dim3(8), dim3(256), 0, stream>>>(theta, E, Einv);
  ln_kernel<<<dim3(4096), dim3(256), 0, stream>>>(x, ln_w, y0, y1, y2);
  conv_w3<<<dim3(1536), dim3(256), 0, stream>>>(attn_w, W0, W1, W2);
  qkv_qk<<<dim3(32, 32), dim3(256), 0, stream>>>(y0, y1, y2, W0, W1, W2, Qf, K0, K1, K2);
  qkv_v<<<dim3(16, 32), dim3(256), 0, stream>>>(y0, y1, W0, W1, VbT);
  attn_kernel<<<dim3(32, 32), dim3(256), 0, stream>>>(Qf, K0, K1, K2, VbT, E, Einv, Ob0, Ob1);
  conv_pw<<<dim3(512), dim3(256), 0, stream>>>(proj_w, PW0, PW1);
  proj_gemm<<<dim3(16, 32), dim3(256), 0, stream>>>(Ob0, Ob1, PW0, PW1, out);
}

// Round 5
// 777.705 us; speedup vs baseline: 1.3339x; 1.3339x over previous
//
#include <hip/hip_runtime.h>
#include <stdint.h>
#include <stddef.h>

typedef __attribute__((ext_vector_type(8))) short short8;
typedef __attribute__((ext_vector_type(4))) float float4v;

#define T_SEQ 2048
#define D_MODEL 1024
#define NH 16
#define HD 64

static __device__ __forceinline__ unsigned short f2bf(float f) {
  unsigned u = __builtin_bit_cast(unsigned, f);
  u += 0x7fffu + ((u >> 16) & 1u);
  return (unsigned short)(u >> 16);
}
static __device__ __forceinline__ float bf2f(unsigned short h) {
  unsigned u = ((unsigned)h) << 16;
  return __builtin_bit_cast(float, u);
}
static __device__ __forceinline__ float4v mfma16(short8 a, short8 b, float4v c) {
  return __builtin_amdgcn_mfma_f32_16x16x32_bf16(a, b, c, 0, 0, 0);
}
// fp32 -> 3 bf16 terms (sum reproduces f to ~2^-27 rel)
static __device__ __forceinline__ void split3(float f, unsigned short& h0,
                                              unsigned short& h1, unsigned short& h2) {
  h0 = f2bf(f);
  float r1 = f - bf2f(h0);
  h1 = f2bf(r1);
  float r2 = r1 - bf2f(h1);
  h2 = f2bf(r2);
}
// fp32 -> 2 bf16 terms (~2^-18 rel)
static __device__ __forceinline__ void split2(float f, unsigned short& h0, unsigned short& h1) {
  h0 = f2bf(f);
  h1 = f2bf(f - bf2f(h0));
}

// ---------------- eta tables ----------------
__global__ void eta_kernel(const float* theta, float* E, float* Einv) {
  int i = blockIdx.x * blockDim.x + threadIdx.x;
  if (i >= T_SEQ) return;
  float th = theta[0];
  float h = log1pf(expf(th));            // softplus
  float t = 1.0f + h * (float)i;         // T0 = 1
  float eta = 3.0f * logf(t);            // C_LOG = 3
  eta = fminf(fmaxf(eta, -50.0f), 50.0f);
  E[i] = expf(eta);
  Einv[i] = expf(-eta);
}

// ---------------- LayerNorm (fp32 in) -> 3-way split y ----------------
__global__ __launch_bounds__(256) void ln_kernel(const float* x, const float* wgt,
                          unsigned short* y0, unsigned short* y1, unsigned short* y2) {
  int row = blockIdx.x;
  int tid = threadIdx.x;
  const float* xr = x + (size_t)row * D_MODEL;
  float v[4];
  float sum = 0.f, ssq = 0.f;
  for (int it = 0; it < 4; ++it) {
    float f = xr[tid + 256 * it];
    v[it] = f;
    sum += f; ssq += f * f;
  }
  for (int off = 32; off >= 1; off >>= 1) {
    sum += __shfl_xor(sum, off, 64);
    ssq += __shfl_xor(ssq, off, 64);
  }
  __shared__ float rs[4], rq[4];
  int w = tid >> 6;
  if ((tid & 63) == 0) { rs[w] = sum; rq[w] = ssq; }
  __syncthreads();
  sum = rs[0] + rs[1] + rs[2] + rs[3];
  ssq = rq[0] + rq[1] + rq[2] + rq[3];
  float mu = sum * (1.0f / D_MODEL);
  float var = ssq * (1.0f / D_MODEL) - mu * mu;
  float rstd = rsqrtf(var + 1e-5f);
  for (int it = 0; it < 4; ++it) {
    int d = tid + 256 * it;
    float y = (v[it] - mu) * rstd * wgt[d];
    unsigned short h0, h1, h2;
    split3(y, h0, h1, h2);
    size_t o = (size_t)row * D_MODEL + d;
    y0[o] = h0; y1[o] = h1; y2[o] = h2;
  }
}

// ---------------- attn_w (fp32) -> split3; W2 only for rows < 2048 (Q,K) ----------------
__global__ __launch_bounds__(256) void conv_w3(const float* src, unsigned short* W0,
                                               unsigned short* W1, unsigned short* W2) {
  size_t base = ((size_t)blockIdx.x * 256 + threadIdx.x) * 8;
  int row = (int)(base >> 10);
  short8 a, b, c;
  for (int j = 0; j < 8; ++j) {
    unsigned short h0, h1, h2;
    split3(src[base + j], h0, h1, h2);
    a[j] = (short)h0; b[j] = (short)h1; c[j] = (short)h2;
  }
  *(short8*)(W0 + base) = a;
  *(short8*)(W1 + base) = b;
  if (row < 2048) *(short8*)(W2 + base) = c;
}

// ---------------- proj_w (fp32) -> split2 ----------------
__global__ __launch_bounds__(256) void conv_pw(const float* src, unsigned short* P0,
                                               unsigned short* P1) {
  size_t base = ((size_t)blockIdx.x * 256 + threadIdx.x) * 8;
  short8 a, b;
  for (int j = 0; j < 8; ++j) {
    unsigned short h0, h1;
    split2(src[base + j], h0, h1);
    a[j] = (short)h0; b[j] = (short)h1;
  }
  *(short8*)(P0 + base) = a;
  *(short8*)(P1 + base) = b;
}

// ---------------- Q,K GEMM: fp32-grade via 6-term split MFMA ----------------
// Q region written fp32; K region written pre-split3 bf16 (K0,K1,K2).
__global__ __launch_bounds__(256) void qkv_qk(
    const unsigned short* y0, const unsigned short* y1, const unsigned short* y2,
    const unsigned short* W0, const unsigned short* W1, const unsigned short* W2,
    float* Qf, unsigned short* K0, unsigned short* K1, unsigned short* K2) {
  int tid = threadIdx.x;
  int w = tid >> 6, lane = tid & 63, q4 = lane >> 4, ln = lane & 15;
  int n0 = blockIdx.x * 64;          // 0..2047
  int m0 = blockIdx.y * 128;
  float4v zero = {0.f, 0.f, 0.f, 0.f};
  float4v acc[2][4];
  for (int mt = 0; mt < 2; ++mt)
    for (int c = 0; c < 4; ++c) acc[mt][c] = zero;

  for (int k0 = 0; k0 < D_MODEL; k0 += 32) {
    short8 a0[2], a1[2], a2[2], b0[4], b1[4], b2[4];
    for (int mt = 0; mt < 2; ++mt) {
      size_t off = (size_t)(m0 + w * 32 + mt * 16 + ln) * D_MODEL + k0 + q4 * 8;
      a0[mt] = *(const short8*)(y0 + off);
      a1[mt] = *(const short8*)(y1 + off);
      a2[mt] = *(const short8*)(y2 + off);
    }
    for (int c = 0; c < 4; ++c) {
      size_t off = (size_t)(n0 + c * 16 + ln) * D_MODEL + k0 + q4 * 8;
      b0[c] = *(const short8*)(W0 + off);
      b1[c] = *(const short8*)(W1 + off);
      b2[c] = *(const short8*)(W2 + off);
    }
    for (int mt = 0; mt < 2; ++mt)
      for (int c = 0; c < 4; ++c) {
        acc[mt][c] = mfma16(a0[mt], b0[c], acc[mt][c]);
        acc[mt][c] = mfma16(a1[mt], b0[c], acc[mt][c]);
        acc[mt][c] = mfma16(a0[mt], b1[c], acc[mt][c]);
        acc[mt][c] = mfma16(a1[mt], b1[c], acc[mt][c]);
        acc[mt][c] = mfma16(a0[mt], b2[c], acc[mt][c]);
        acc[mt][c] = mfma16(a2[mt], b0[c], acc[mt][c]);
      }
  }
  int region = n0 >> 10;            // 0=Q 1=K
  int h = (n0 & 1023) >> 6;
  for (int mt = 0; mt < 2; ++mt)
    for (int c = 0; c < 4; ++c)
      for (int r = 0; r < 4; ++r) {
        int gm = m0 + w * 32 + mt * 16 + q4 * 4 + r;
        int bi = gm >> 11, t = gm & 2047;
        int d = c * 16 + ln;
        size_t o = ((size_t)(bi * NH + h) * T_SEQ + t) * HD + d;
        float val = acc[mt][c][r];
        if (region == 0) {
          Qf[o] = val;
        } else {
          unsigned short h0, h1, h2;
          split3(val, h0, h1, h2);
          K0[o] = h0; K1[o] = h1; K2[o] = h2;
        }
      }
}

// ---------------- V GEMM (3-term, bf16-out, transposed [b,h,d,t]) ----------------
__global__ __launch_bounds__(256) void qkv_v(
    const unsigned short* y0, const unsigned short* y1,
    const unsigned short* W0, const unsigned short* W1, unsigned short* VbT) {
  int tid = threadIdx.x;
  int w = tid >> 6, lane = tid & 63, q4 = lane >> 4, ln = lane & 15;
  int n0 = 2048 + blockIdx.x * 64;   // V region rows of attn_w
  int m0 = blockIdx.y * 128;
  float4v zero = {0.f, 0.f, 0.f, 0.f};
  float4v acc[2][4];
  for (int mt = 0; mt < 2; ++mt)
    for (int c = 0; c < 4; ++c) acc[mt][c] = zero;

  for (int k0 = 0; k0 < D_MODEL; k0 += 32) {
    short8 a0[2], a1[2], b0[4], b1[4];
    for (int mt = 0; mt < 2; ++mt) {
      size_t off = (size_t)(m0 + w * 32 + mt * 16 + ln) * D_MODEL + k0 + q4 * 8;
      a0[mt] = *(const short8*)(y0 + off);
      a1[mt] = *(const short8*)(y1 + off);
    }
    for (int c = 0; c < 4; ++c) {
      size_t off = (size_t)(n0 + c * 16 + ln) * D_MODEL + k0 + q4 * 8;
      b0[c] = *(const short8*)(W0 + off);
      b1[c] = *(const short8*)(W1 + off);
    }
    for (int mt = 0; mt < 2; ++mt)
      for (int c = 0; c < 4; ++c) {
        acc[mt][c] = mfma16(a0[mt], b0[c], acc[mt][c]);
        acc[mt][c] = mfma16(a1[mt], b0[c], acc[mt][c]);
        acc[mt][c] = mfma16(a0[mt], b1[c], acc[mt][c]);
      }
  }
  int h = (n0 & 1023) >> 6;
  for (int mt = 0; mt < 2; ++mt)
    for (int c = 0; c < 4; ++c) {
      int tb = m0 + w * 32 + mt * 16 + q4 * 4;   // 4 consecutive t
      int bi = tb >> 11, t = tb & 2047;
      int d = c * 16 + ln;
      unsigned short tmp[4];
      for (int r = 0; r < 4; ++r) tmp[r] = f2bf(acc[mt][c][r]);
      *(uint64_t*)(VbT + ((size_t)((bi * NH + h) * HD + d) * T_SEQ + t)) =
          *(const uint64_t*)tmp;
    }
}

// ---------------- fused causal attention (flash-style, fp32-grade S) ----------------
// Barrier-free: each wave owns a 16-row q-tile and its private Plds slice.
// Load-balanced: block x processes q-tile pair (x, 31-x) => exactly 33 jt-iters/block.
__global__ __launch_bounds__(256) void attn_kernel(
    const float* Qf, const unsigned short* K0, const unsigned short* K1,
    const unsigned short* K2, const unsigned short* VbT,
    const float* E, const float* Einv, unsigned short* Ob0, unsigned short* Ob1) {
  __shared__ unsigned short Plds[4][16][72];   // per-wave P tile, padded
  int tid = threadIdx.x;
  int w = tid >> 6, lane = tid & 63, q4 = lane >> 4, ln = lane & 15;
  int px = blockIdx.x;                  // 0..15
  int bh = blockIdx.y;
  const float* Qb = Qf + (size_t)bh * T_SEQ * HD;
  size_t kbase = (size_t)bh * T_SEQ * HD;
  const unsigned short* Vb = VbT + (size_t)bh * HD * T_SEQ;
  int b = bh >> 4, hh = bh & 15;
  float4v zero = {0.f, 0.f, 0.f, 0.f};

  for (int half = 0; half < 2; ++half) {
    int qt = half ? (31 - px) : px;
    int q0 = qt * 64;
    int ibase = q0 + w * 16;

    // Q fragments, 3-way split (once per tile; K is pre-split in memory)
    short8 qa[2][3];
    {
      const float* qp = Qb + (size_t)(ibase + ln) * HD;
      for (int ks = 0; ks < 2; ++ks) {
        float f[8];
        *(float4v*)&f[0] = *(const float4v*)(qp + ks * 32 + q4 * 8);
        *(float4v*)&f[4] = *(const float4v*)(qp + ks * 32 + q4 * 8 + 4);
        for (int j = 0; j < 8; ++j) {
          unsigned short h0, h1, h2;
          split3(f[j], h0, h1, h2);
          qa[ks][0][j] = (short)h0; qa[ks][1][j] = (short)h1; qa[ks][2][j] = (short)h2;
        }
      }
    }
    float ei[4];
    for (int r = 0; r < 4; ++r) ei[r] = E[ibase + q4 * 4 + r] * 0.125f; // fold 1/sqrt(64)

    float m_r[4] = {-3e38f, -3e38f, -3e38f, -3e38f};
    float l_r[4] = {0.f, 0.f, 0.f, 0.f};
    float4v oacc[4];
    for (int c = 0; c < 4; ++c) oacc[c] = zero;

    for (int jt = 0; jt <= qt; ++jt) {
      int j0 = jt * 64;
      bool diag = (jt == qt);
      float p[4][4];   // [c][r]: logits, then probabilities
      for (int c = 0; c < 4; ++c) {
        int jrow = j0 + c * 16 + ln;
        size_t ko = kbase + (size_t)jrow * HD;
        float4v s = zero;
        for (int ks = 0; ks < 2; ++ks) {
          size_t off = ko + ks * 32 + q4 * 8;
          short8 k0v = *(const short8*)(K0 + off);
          short8 k1v = *(const short8*)(K1 + off);
          short8 k2v = *(const short8*)(K2 + off);
          // 6-term split product: fp32-grade S
          s = mfma16(qa[ks][0], k0v, s);
          s = mfma16(qa[ks][1], k0v, s);
          s = mfma16(qa[ks][0], k1v, s);
          s = mfma16(qa[ks][1], k1v, s);
          s = mfma16(qa[ks][0], k2v, s);
          s = mfma16(qa[ks][2], k0v, s);
        }
        float ein = Einv[jrow];
        for (int r = 0; r < 4; ++r) {
          float l = s[r] * ei[r] * ein;
          if (diag && jrow > ibase + q4 * 4 + r) l = -3e38f;   // causal mask
          p[c][r] = l;
        }
      }
      // online softmax (each row lives on the 16 lanes sharing q4)
      float alpha[4], mnew[4];
      for (int r = 0; r < 4; ++r) {
        float tm = fmaxf(fmaxf(p[0][r], p[1][r]), fmaxf(p[2][r], p[3][r]));
        for (int off = 8; off >= 1; off >>= 1) tm = fmaxf(tm, __shfl_xor(tm, off, 16));
        mnew[r] = fmaxf(m_r[r], tm);
        alpha[r] = expf(m_r[r] - mnew[r]);
        m_r[r] = mnew[r];
      }
      float rssum[4] = {0.f, 0.f, 0.f, 0.f};
      for (int c = 0; c < 4; ++c)
        for (int r = 0; r < 4; ++r) {
          float pv = expf(p[c][r] - mnew[r]);
          p[c][r] = pv;
          rssum[r] += pv;
        }
      for (int r = 0; r < 4; ++r) {
        for (int off = 8; off >= 1; off >>= 1) rssum[r] += __shfl_xor(rssum[r], off, 16);
        l_r[r] = l_r[r] * alpha[r] + rssum[r];
      }
      for (int c = 0; c < 4; ++c)
        for (int r = 0; r < 4; ++r) oacc[c][r] *= alpha[r];

      // within-wave LDS transpose (C-layout -> A-layout); LDS pipe is in-order
      // per wave, so only compiler reordering must be fenced.
      __asm__ __volatile__("" ::: "memory");
      for (int c = 0; c < 4; ++c)
        for (int r = 0; r < 4; ++r)
          Plds[w][q4 * 4 + r][c * 16 + ln] = f2bf(p[c][r]);
      __asm__ __volatile__("" ::: "memory");

      // P·V (V fragments directly from transposed global layout)
      for (int ks = 0; ks < 2; ++ks) {
        short8 pa = *(const short8*)&Plds[w][ln][ks * 32 + q4 * 8];
        for (int c = 0; c < 4; ++c) {
          short8 vb = *(const short8*)(Vb + (size_t)(c * 16 + ln) * T_SEQ + j0 + ks * 32 + q4 * 8);
          oacc[c] = mfma16(pa, vb, oacc[c]);
        }
      }
      __asm__ __volatile__("" ::: "memory");   // reads done before next-iter overwrite
    }
    for (int c = 0; c < 4; ++c)
      for (int r = 0; r < 4; ++r) {
        int i = ibase + q4 * 4 + r;
        float val = oacc[c][r] / l_r[r];
        unsigned short h0, h1;
        split2(val, h0, h1);
        size_t o = ((size_t)(b * T_SEQ + i)) * D_MODEL + hh * 64 + c * 16 + ln;
        Ob0[o] = h0; Ob1[o] = h1;
      }
  }
}

// ---------------- output projection (3-term split, fp32 out) ----------------
__global__ __launch_bounds__(256) void proj_gemm(
    const unsigned short* A0, const unsigned short* A1,
    const unsigned short* P0, const unsigned short* P1, float* out) {
  int tid = threadIdx.x;
  int w = tid >> 6, lane = tid & 63, q4 = lane >> 4, ln = lane & 15;
  int n0 = blockIdx.x * 64;
  int m0 = blockIdx.y * 128;
  float4v zero = {0.f, 0.f, 0.f, 0.f};
  float4v acc[2][4];
  for (int mt = 0; mt < 2; ++mt)
    for (int c = 0; c < 4; ++c) acc[mt][c] = zero;

  for (int k0 = 0; k0 < D_MODEL; k0 += 32) {
    short8 a0[2], a1[2], b0[4], b1[4];
    for (int mt = 0; mt < 2; ++mt) {
      size_t off = (size_t)(m0 + w * 32 + mt * 16 + ln) * D_MODEL + k0 + q4 * 8;
      a0[mt] = *(const short8*)(A0 + off);
      a1[mt] = *(const short8*)(A1 + off);
    }
    for (int c = 0; c < 4; ++c) {
      size_t off = (size_t)(n0 + c * 16 + ln) * D_MODEL + k0 + q4 * 8;
      b0[c] = *(const short8*)(P0 + off);
      b1[c] = *(const short8*)(P1 + off);
    }
    for (int mt = 0; mt < 2; ++mt)
      for (int c = 0; c < 4; ++c) {
        acc[mt][c] = mfma16(a0[mt], b0[c], acc[mt][c]);
        acc[mt][c] = mfma16(a1[mt], b0[c], acc[mt][c]);
        acc[mt][c] = mfma16(a0[mt], b1[c], acc[mt][c]);
      }
  }
  for (int mt = 0; mt < 2; ++mt)
    for (int c = 0; c < 4; ++c)
      for (int r = 0; r < 4; ++r) {
        int gm = m0 + w * 32 + mt * 16 + q4 * 4 + r;
        out[(size_t)gm * D_MODEL + n0 + c * 16 + ln] = acc[mt][c][r];
      }
}

extern "C" void kernel_launch(void* const* d_in, const int* in_sizes, int n_in,
                              void* d_out, int out_size, void* d_ws, size_t ws_size,
                              hipStream_t stream) {
  const float* x      = (const float*)d_in[0];
  const float* ln_w   = (const float*)d_in[1];
  const float* attn_w = (const float*)d_in[2];
  const float* proj_w = (const float*)d_in[3];
  const float* theta  = (const float*)d_in[4];
  float* out = (float*)d_out;

  char* ws = (char*)d_ws;
  const size_t SZY  = (size_t)4096 * 1024 * 2;        // 8,388,608
  const size_t SZW  = (size_t)3072 * 1024 * 2;        // 6,291,456
  const size_t SZW2 = (size_t)2048 * 1024 * 2;        // 4,194,304
  const size_t SZQ  = (size_t)2 * 16 * 2048 * 64 * 4; // 16,777,216 (fp32)
  const size_t SZK  = (size_t)2 * 16 * 2048 * 64 * 2; //  8,388,608 (bf16)

  unsigned short* y0 = (unsigned short*)(ws);
  unsigned short* y1 = (unsigned short*)(ws + SZY);
  unsigned short* y2 = (unsigned short*)(ws + 2 * SZY);
  unsigned short* W0 = (unsigned short*)(ws + 3 * SZY);
  unsigned short* W1 = (unsigned short*)(ws + 3 * SZY + SZW);
  unsigned short* W2 = (unsigned short*)(ws + 3 * SZY + 2 * SZW);
  float* Qf          = (float*)(ws + 3 * SZY + 2 * SZW + SZW2);
  unsigned short* K0 = (unsigned short*)(ws + 3 * SZY + 2 * SZW + SZW2 + SZQ);
  unsigned short* K1 = (unsigned short*)(ws + 3 * SZY + 2 * SZW + SZW2 + SZQ + SZK);
  float* E           = (float*)(ws + 3 * SZY + 2 * SZW + SZW2 + SZQ + 2 * SZK);
  float* Einv        = E + T_SEQ;
  // aliases into dead regions (y dead after qkv_*, then reused):
  unsigned short* Ob0 = y0;
  unsigned short* Ob1 = y1;
  unsigned short* PW0 = y2;
  unsigned short* PW1 = y2 + (size_t)1024 * 1024;
  // d_out scratch (16.78 MB): VbT low half, K2 high half; both dead before proj writes
  unsigned short* VbT = (unsigned short*)d_out;
  unsigned short* K2  = (unsigned short*)((char*)d_out + SZK);

  size_t needed = 3 * SZY + 2 * SZW + SZW2 + SZQ + 2 * SZK + 2 * T_SEQ * 4;  // 75,513,856
  if (ws_size < needed) return;  // loud failure: output stays zero

  eta_kernel<<<dim3(8), dim3(256), 0, stream>>>(theta, E, Einv);
  ln_kernel<<<dim3(4096), dim3(256), 0, stream>>>(x, ln_w, y0, y1, y2);
  conv_w3<<<dim3(1536), dim3(256), 0, stream>>>(attn_w, W0, W1, W2);
  qkv_qk<<<dim3(32, 32), dim3(256), 0, stream>>>(y0, y1, y2, W0, W1, W2, Qf, K0, K1, K2);
  qkv_v<<<dim3(16, 32), dim3(256), 0, stream>>>(y0, y1, W0, W1, VbT);
  attn_kernel<<<dim3(16, 32), dim3(256), 0, stream>>>(Qf, K0, K1, K2, VbT, E, Einv, Ob0, Ob1);
  conv_pw<<<dim3(512), dim3(256), 0, stream>>>(proj_w, PW0, PW1);
  proj_gemm<<<dim3(16, 32), dim3(256), 0, stream>>>(Ob0, Ob1, PW0, PW1, out);
}

// Round 6
// 675.449 us; speedup vs baseline: 1.5358x; 1.1514x over previous
//
#include <hip/hip_runtime.h>
#include <stdint.h>
#include <stddef.h>

typedef __attribute__((ext_vector_type(8))) short short8;
typedef __attribute__((ext_vector_type(4))) float float4v;

#define T_SEQ 2048
#define D_MODEL 1024
#define NH 16
#define HD 64

static __device__ __forceinline__ unsigned short f2bf(float f) {
  unsigned u = __builtin_bit_cast(unsigned, f);
  u += 0x7fffu + ((u >> 16) & 1u);
  return (unsigned short)(u >> 16);
}
static __device__ __forceinline__ float bf2f(unsigned short h) {
  unsigned u = ((unsigned)h) << 16;
  return __builtin_bit_cast(float, u);
}
static __device__ __forceinline__ float4v mfma16(short8 a, short8 b, float4v c) {
  return __builtin_amdgcn_mfma_f32_16x16x32_bf16(a, b, c, 0, 0, 0);
}
// fp32 -> 3 bf16 terms (sum reproduces f to ~2^-27 rel)
static __device__ __forceinline__ void split3(float f, unsigned short& h0,
                                              unsigned short& h1, unsigned short& h2) {
  h0 = f2bf(f);
  float r1 = f - bf2f(h0);
  h1 = f2bf(r1);
  float r2 = r1 - bf2f(h1);
  h2 = f2bf(r2);
}
// fp32 -> 2 bf16 terms (~2^-18 rel)
static __device__ __forceinline__ void split2(float f, unsigned short& h0, unsigned short& h1) {
  h0 = f2bf(f);
  h1 = f2bf(f - bf2f(h0));
}

// async global->LDS, 16 B per lane (global_load_lds_dwordx4); guarded fallback
static __device__ __forceinline__ void stage16(const unsigned short* g, unsigned short* l) {
#if __has_builtin(__builtin_amdgcn_global_load_lds)
  __builtin_amdgcn_global_load_lds(
      (const __attribute__((address_space(1))) unsigned int*)g,
      (__attribute__((address_space(3))) unsigned int*)l, 16, 0, 0);
#else
  *(short8*)l = *(const short8*)g;
#endif
}

// ---------------- eta tables ----------------
__global__ void eta_kernel(const float* theta, float* E, float* Einv) {
  int i = blockIdx.x * blockDim.x + threadIdx.x;
  if (i >= T_SEQ) return;
  float th = theta[0];
  float h = log1pf(expf(th));            // softplus
  float t = 1.0f + h * (float)i;         // T0 = 1
  float eta = 3.0f * logf(t);            // C_LOG = 3
  eta = fminf(fmaxf(eta, -50.0f), 50.0f);
  E[i] = expf(eta);
  Einv[i] = expf(-eta);
}

// ---------------- LayerNorm (fp32 in) -> 3-way split y ----------------
__global__ __launch_bounds__(256) void ln_kernel(const float* x, const float* wgt,
                          unsigned short* y0, unsigned short* y1, unsigned short* y2) {
  int row = blockIdx.x;
  int tid = threadIdx.x;
  const float* xr = x + (size_t)row * D_MODEL;
  float v[4];
  float sum = 0.f, ssq = 0.f;
  for (int it = 0; it < 4; ++it) {
    float f = xr[tid + 256 * it];
    v[it] = f;
    sum += f; ssq += f * f;
  }
  for (int off = 32; off >= 1; off >>= 1) {
    sum += __shfl_xor(sum, off, 64);
    ssq += __shfl_xor(ssq, off, 64);
  }
  __shared__ float rs[4], rq[4];
  int w = tid >> 6;
  if ((tid & 63) == 0) { rs[w] = sum; rq[w] = ssq; }
  __syncthreads();
  sum = rs[0] + rs[1] + rs[2] + rs[3];
  ssq = rq[0] + rq[1] + rq[2] + rq[3];
  float mu = sum * (1.0f / D_MODEL);
  float var = ssq * (1.0f / D_MODEL) - mu * mu;
  float rstd = rsqrtf(var + 1e-5f);
  for (int it = 0; it < 4; ++it) {
    int d = tid + 256 * it;
    float y = (v[it] - mu) * rstd * wgt[d];
    unsigned short h0, h1, h2;
    split3(y, h0, h1, h2);
    size_t o = (size_t)row * D_MODEL + d;
    y0[o] = h0; y1[o] = h1; y2[o] = h2;
  }
}

// ---------------- attn_w (fp32) -> split3; W2 only for rows < 2048 (Q,K) ----------------
__global__ __launch_bounds__(256) void conv_w3(const float* src, unsigned short* W0,
                                               unsigned short* W1, unsigned short* W2) {
  size_t base = ((size_t)blockIdx.x * 256 + threadIdx.x) * 8;
  int row = (int)(base >> 10);
  short8 a, b, c;
  for (int j = 0; j < 8; ++j) {
    unsigned short h0, h1, h2;
    split3(src[base + j], h0, h1, h2);
    a[j] = (short)h0; b[j] = (short)h1; c[j] = (short)h2;
  }
  *(short8*)(W0 + base) = a;
  *(short8*)(W1 + base) = b;
  if (row < 2048) *(short8*)(W2 + base) = c;
}

// ---------------- proj_w (fp32) -> split2 ----------------
__global__ __launch_bounds__(256) void conv_pw(const float* src, unsigned short* P0,
                                               unsigned short* P1) {
  size_t base = ((size_t)blockIdx.x * 256 + threadIdx.x) * 8;
  short8 a, b;
  for (int j = 0; j < 8; ++j) {
    unsigned short h0, h1;
    split2(src[base + j], h0, h1);
    a[j] = (short)h0; b[j] = (short)h1;
  }
  *(short8*)(P0 + base) = a;
  *(short8*)(P1 + base) = b;
}

// ---------------- Q,K GEMM: m97-style LDS-staged 128x128 tile, 6-term split ----------------
__global__ __launch_bounds__(256) void qkv_qk(
    const unsigned short* y0, const unsigned short* y1, const unsigned short* y2,
    const unsigned short* W0, const unsigned short* W1, const unsigned short* W2,
    float* Qf, unsigned short* K0, unsigned short* K1, unsigned short* K2) {
  __shared__ unsigned short As[3][128 * 32];   // 8 KB each
  __shared__ unsigned short Bs[3][128 * 32];
  int tid = threadIdx.x;
  int w = tid >> 6, lane = tid & 63, q4 = lane >> 4, ln = lane & 15;
  int wr = w >> 1, wc = w & 1;
  int n0g = blockIdx.x * 128;   // 0..2047 (Q then K region)
  int m0 = blockIdx.y * 128;
  const unsigned short* Asrc[3] = {y0, y1, y2};
  const unsigned short* Bsrc[3] = {W0, W1, W2};

  float4v zero = {0.f, 0.f, 0.f, 0.f};
  float4v acc[4][4];
  for (int mt = 0; mt < 4; ++mt)
    for (int ct = 0; ct < 4; ++ct) acc[mt][ct] = zero;

  int srow = tid >> 2;          // 0..63
  int kpart = tid & 3;          // 0..3
  unsigned lds_off = (unsigned)tid * 16;   // bytes; == (srow*64 + kpart*16)

  for (int k0 = 0; k0 < D_MODEL; k0 += 32) {
    __syncthreads();   // prev round's ds_reads done before overwrite
    for (int i = 0; i < 2; ++i) {
      size_t arow = (size_t)(m0 + srow + i * 64) * D_MODEL + k0 + kpart * 8;
      size_t brow = (size_t)(n0g + srow + i * 64) * D_MODEL + k0 + kpart * 8;
      for (int s = 0; s < 3; ++s) {
        stage16(Asrc[s] + arow, (unsigned short*)((char*)As[s] + lds_off + i * 4096));
        stage16(Bsrc[s] + brow, (unsigned short*)((char*)Bs[s] + lds_off + i * 4096));
      }
    }
    __syncthreads();   // staging visible (vmcnt(0) drained by barrier)

    short8 af[4][3];
    for (int mt = 0; mt < 4; ++mt)
      for (int s = 0; s < 3; ++s)
        af[mt][s] = *(const short8*)&As[s][(wr * 64 + mt * 16 + ln) * 32 + q4 * 8];
    for (int ct = 0; ct < 4; ++ct) {
      int brow = (wc * 64 + ct * 16 + ln) * 32 + q4 * 8;
      short8 b0 = *(const short8*)&Bs[0][brow];
      short8 b1 = *(const short8*)&Bs[1][brow];
      short8 b2 = *(const short8*)&Bs[2][brow];
      for (int mt = 0; mt < 4; ++mt) {
        float4v a = acc[mt][ct];
        a = mfma16(af[mt][0], b0, a);
        a = mfma16(af[mt][1], b0, a);
        a = mfma16(af[mt][0], b1, a);
        a = mfma16(af[mt][1], b1, a);
        a = mfma16(af[mt][0], b2, a);
        a = mfma16(af[mt][2], b0, a);
        acc[mt][ct] = a;
      }
    }
  }

  int region = n0g >> 10;            // 0=Q 1=K (128-tile never straddles)
  for (int mt = 0; mt < 4; ++mt)
    for (int ct = 0; ct < 4; ++ct)
      for (int r = 0; r < 4; ++r) {
        int gm = m0 + wr * 64 + mt * 16 + q4 * 4 + r;
        int col = n0g + wc * 64 + ct * 16 + ln;
        int bi = gm >> 11, t = gm & 2047;
        int h = (col & 1023) >> 6, d = col & 63;
        size_t o = ((size_t)(bi * NH + h) * T_SEQ + t) * HD + d;
        float val = acc[mt][ct][r];
        if (region == 0) {
          Qf[o] = val;
        } else {
          unsigned short h0, h1, h2;
          split3(val, h0, h1, h2);
          K0[o] = h0; K1[o] = h1; K2[o] = h2;
        }
      }
}

// ---------------- V GEMM: LDS-staged, 3-term, bf16-out transposed [b,h,d,t] ----------------
__global__ __launch_bounds__(256) void qkv_v(
    const unsigned short* y0, const unsigned short* y1,
    const unsigned short* W0, const unsigned short* W1, unsigned short* VbT) {
  __shared__ unsigned short As[2][128 * 32];
  __shared__ unsigned short Bs[2][128 * 32];
  int tid = threadIdx.x;
  int w = tid >> 6, lane = tid & 63, q4 = lane >> 4, ln = lane & 15;
  int wr = w >> 1, wc = w & 1;
  int n0g = blockIdx.x * 128;        // 0..1023 within V region
  int m0 = blockIdx.y * 128;
  const unsigned short* Asrc[2] = {y0, y1};
  const unsigned short* Bsrc[2] = {W0, W1};

  float4v zero = {0.f, 0.f, 0.f, 0.f};
  float4v acc[4][4];
  for (int mt = 0; mt < 4; ++mt)
    for (int ct = 0; ct < 4; ++ct) acc[mt][ct] = zero;

  int srow = tid >> 2, kpart = tid & 3;
  unsigned lds_off = (unsigned)tid * 16;

  for (int k0 = 0; k0 < D_MODEL; k0 += 32) {
    __syncthreads();
    for (int i = 0; i < 2; ++i) {
      size_t arow = (size_t)(m0 + srow + i * 64) * D_MODEL + k0 + kpart * 8;
      size_t brow = (size_t)(2048 + n0g + srow + i * 64) * D_MODEL + k0 + kpart * 8;
      for (int s = 0; s < 2; ++s) {
        stage16(Asrc[s] + arow, (unsigned short*)((char*)As[s] + lds_off + i * 4096));
        stage16(Bsrc[s] + brow, (unsigned short*)((char*)Bs[s] + lds_off + i * 4096));
      }
    }
    __syncthreads();

    short8 af[4][2];
    for (int mt = 0; mt < 4; ++mt)
      for (int s = 0; s < 2; ++s)
        af[mt][s] = *(const short8*)&As[s][(wr * 64 + mt * 16 + ln) * 32 + q4 * 8];
    for (int ct = 0; ct < 4; ++ct) {
      int brow = (wc * 64 + ct * 16 + ln) * 32 + q4 * 8;
      short8 b0 = *(const short8*)&Bs[0][brow];
      short8 b1 = *(const short8*)&Bs[1][brow];
      for (int mt = 0; mt < 4; ++mt) {
        float4v a = acc[mt][ct];
        a = mfma16(af[mt][0], b0, a);
        a = mfma16(af[mt][1], b0, a);
        a = mfma16(af[mt][0], b1, a);
        acc[mt][ct] = a;
      }
    }
  }

  for (int mt = 0; mt < 4; ++mt)
    for (int ct = 0; ct < 4; ++ct) {
      int tb = m0 + wr * 64 + mt * 16 + q4 * 4;   // 4 consecutive t
      int bi = tb >> 11, t = tb & 2047;
      int col = n0g + wc * 64 + ct * 16 + ln;
      int h = col >> 6, d = col & 63;
      unsigned short tmp[4];
      for (int r = 0; r < 4; ++r) tmp[r] = f2bf(acc[mt][ct][r]);
      *(uint64_t*)(VbT + ((size_t)((bi * NH + h) * HD + d) * T_SEQ + t)) =
          *(const uint64_t*)tmp;
    }
}

// ---------------- fused causal attention (flash-style, fp32-grade S) ----------------
// Barrier-free: each wave owns a 16-row q-tile and its private Plds slice.
// Load-balanced: block x processes q-tile pair (x, 31-x) => exactly 33 jt-iters/block.
__global__ __launch_bounds__(256) void attn_kernel(
    const float* Qf, const unsigned short* K0, const unsigned short* K1,
    const unsigned short* K2, const unsigned short* VbT,
    const float* E, const float* Einv, unsigned short* Ob0, unsigned short* Ob1) {
  __shared__ unsigned short Plds[4][16][72];   // per-wave P tile, padded
  int tid = threadIdx.x;
  int w = tid >> 6, lane = tid & 63, q4 = lane >> 4, ln = lane & 15;
  int px = blockIdx.x;                  // 0..15
  int bh = blockIdx.y;
  const float* Qb = Qf + (size_t)bh * T_SEQ * HD;
  size_t kbase = (size_t)bh * T_SEQ * HD;
  const unsigned short* Vb = VbT + (size_t)bh * HD * T_SEQ;
  int b = bh >> 4, hh = bh & 15;
  float4v zero = {0.f, 0.f, 0.f, 0.f};

  for (int half = 0; half < 2; ++half) {
    int qt = half ? (31 - px) : px;
    int q0 = qt * 64;
    int ibase = q0 + w * 16;

    short8 qa[2][3];
    {
      const float* qp = Qb + (size_t)(ibase + ln) * HD;
      for (int ks = 0; ks < 2; ++ks) {
        float f[8];
        *(float4v*)&f[0] = *(const float4v*)(qp + ks * 32 + q4 * 8);
        *(float4v*)&f[4] = *(const float4v*)(qp + ks * 32 + q4 * 8 + 4);
        for (int j = 0; j < 8; ++j) {
          unsigned short h0, h1, h2;
          split3(f[j], h0, h1, h2);
          qa[ks][0][j] = (short)h0; qa[ks][1][j] = (short)h1; qa[ks][2][j] = (short)h2;
        }
      }
    }
    float ei[4];
    for (int r = 0; r < 4; ++r) ei[r] = E[ibase + q4 * 4 + r] * 0.125f; // fold 1/sqrt(64)

    float m_r[4] = {-3e38f, -3e38f, -3e38f, -3e38f};
    float l_r[4] = {0.f, 0.f, 0.f, 0.f};
    float4v oacc[4];
    for (int c = 0; c < 4; ++c) oacc[c] = zero;

    for (int jt = 0; jt <= qt; ++jt) {
      int j0 = jt * 64;
      bool diag = (jt == qt);
      float p[4][4];   // [c][r]: logits, then probabilities
      for (int c = 0; c < 4; ++c) {
        int jrow = j0 + c * 16 + ln;
        size_t ko = kbase + (size_t)jrow * HD;
        float4v s = zero;
        for (int ks = 0; ks < 2; ++ks) {
          size_t off = ko + ks * 32 + q4 * 8;
          short8 k0v = *(const short8*)(K0 + off);
          short8 k1v = *(const short8*)(K1 + off);
          short8 k2v = *(const short8*)(K2 + off);
          s = mfma16(qa[ks][0], k0v, s);
          s = mfma16(qa[ks][1], k0v, s);
          s = mfma16(qa[ks][0], k1v, s);
          s = mfma16(qa[ks][1], k1v, s);
          s = mfma16(qa[ks][0], k2v, s);
          s = mfma16(qa[ks][2], k0v, s);
        }
        float ein = Einv[jrow];
        for (int r = 0; r < 4; ++r) {
          float l = s[r] * ei[r] * ein;
          if (diag && jrow > ibase + q4 * 4 + r) l = -3e38f;   // causal mask
          p[c][r] = l;
        }
      }
      float alpha[4], mnew[4];
      for (int r = 0; r < 4; ++r) {
        float tm = fmaxf(fmaxf(p[0][r], p[1][r]), fmaxf(p[2][r], p[3][r]));
        for (int off = 8; off >= 1; off >>= 1) tm = fmaxf(tm, __shfl_xor(tm, off, 16));
        mnew[r] = fmaxf(m_r[r], tm);
        alpha[r] = expf(m_r[r] - mnew[r]);
        m_r[r] = mnew[r];
      }
      float rssum[4] = {0.f, 0.f, 0.f, 0.f};
      for (int c = 0; c < 4; ++c)
        for (int r = 0; r < 4; ++r) {
          float pv = expf(p[c][r] - mnew[r]);
          p[c][r] = pv;
          rssum[r] += pv;
        }
      for (int r = 0; r < 4; ++r) {
        for (int off = 8; off >= 1; off >>= 1) rssum[r] += __shfl_xor(rssum[r], off, 16);
        l_r[r] = l_r[r] * alpha[r] + rssum[r];
      }
      for (int c = 0; c < 4; ++c)
        for (int r = 0; r < 4; ++r) oacc[c][r] *= alpha[r];

      __asm__ __volatile__("" ::: "memory");
      for (int c = 0; c < 4; ++c)
        for (int r = 0; r < 4; ++r)
          Plds[w][q4 * 4 + r][c * 16 + ln] = f2bf(p[c][r]);
      __asm__ __volatile__("" ::: "memory");

      for (int ks = 0; ks < 2; ++ks) {
        short8 pa = *(const short8*)&Plds[w][ln][ks * 32 + q4 * 8];
        for (int c = 0; c < 4; ++c) {
          short8 vb = *(const short8*)(Vb + (size_t)(c * 16 + ln) * T_SEQ + j0 + ks * 32 + q4 * 8);
          oacc[c] = mfma16(pa, vb, oacc[c]);
        }
      }
      __asm__ __volatile__("" ::: "memory");
    }
    for (int c = 0; c < 4; ++c)
      for (int r = 0; r < 4; ++r) {
        int i = ibase + q4 * 4 + r;
        float val = oacc[c][r] / l_r[r];
        unsigned short h0, h1;
        split2(val, h0, h1);
        size_t o = ((size_t)(b * T_SEQ + i)) * D_MODEL + hh * 64 + c * 16 + ln;
        Ob0[o] = h0; Ob1[o] = h1;
      }
  }
}

// ---------------- output projection: LDS-staged, 3-term, fp32 out ----------------
__global__ __launch_bounds__(256) void proj_gemm(
    const unsigned short* A0, const unsigned short* A1,
    const unsigned short* P0, const unsigned short* P1, float* out) {
  __shared__ unsigned short As[2][128 * 32];
  __shared__ unsigned short Bs[2][128 * 32];
  int tid = threadIdx.x;
  int w = tid >> 6, lane = tid & 63, q4 = lane >> 4, ln = lane & 15;
  int wr = w >> 1, wc = w & 1;
  int n0g = blockIdx.x * 128;
  int m0 = blockIdx.y * 128;
  const unsigned short* Asrc[2] = {A0, A1};
  const unsigned short* Bsrc[2] = {P0, P1};

  float4v zero = {0.f, 0.f, 0.f, 0.f};
  float4v acc[4][4];
  for (int mt = 0; mt < 4; ++mt)
    for (int ct = 0; ct < 4; ++ct) acc[mt][ct] = zero;

  int srow = tid >> 2, kpart = tid & 3;
  unsigned lds_off = (unsigned)tid * 16;

  for (int k0 = 0; k0 < D_MODEL; k0 += 32) {
    __syncthreads();
    for (int i = 0; i < 2; ++i) {
      size_t arow = (size_t)(m0 + srow + i * 64) * D_MODEL + k0 + kpart * 8;
      size_t brow = (size_t)(n0g + srow + i * 64) * D_MODEL + k0 + kpart * 8;
      for (int s = 0; s < 2; ++s) {
        stage16(Asrc[s] + arow, (unsigned short*)((char*)As[s] + lds_off + i * 4096));
        stage16(Bsrc[s] + brow, (unsigned short*)((char*)Bs[s] + lds_off + i * 4096));
      }
    }
    __syncthreads();

    short8 af[4][2];
    for (int mt = 0; mt < 4; ++mt)
      for (int s = 0; s < 2; ++s)
        af[mt][s] = *(const short8*)&As[s][(wr * 64 + mt * 16 + ln) * 32 + q4 * 8];
    for (int ct = 0; ct < 4; ++ct) {
      int brow = (wc * 64 + ct * 16 + ln) * 32 + q4 * 8;
      short8 b0 = *(const short8*)&Bs[0][brow];
      short8 b1 = *(const short8*)&Bs[1][brow];
      for (int mt = 0; mt < 4; ++mt) {
        float4v a = acc[mt][ct];
        a = mfma16(af[mt][0], b0, a);
        a = mfma16(af[mt][1], b0, a);
        a = mfma16(af[mt][0], b1, a);
        acc[mt][ct] = a;
      }
    }
  }

  for (int mt = 0; mt < 4; ++mt)
    for (int ct = 0; ct < 4; ++ct)
      for (int r = 0; r < 4; ++r) {
        int gm = m0 + wr * 64 + mt * 16 + q4 * 4 + r;
        int col = n0g + wc * 64 + ct * 16 + ln;
        out[(size_t)gm * D_MODEL + col] = acc[mt][ct][r];
      }
}

extern "C" void kernel_launch(void* const* d_in, const int* in_sizes, int n_in,
                              void* d_out, int out_size, void* d_ws, size_t ws_size,
                              hipStream_t stream) {
  const float* x      = (const float*)d_in[0];
  const float* ln_w   = (const float*)d_in[1];
  const float* attn_w = (const float*)d_in[2];
  const float* proj_w = (const float*)d_in[3];
  const float* theta  = (const float*)d_in[4];
  float* out = (float*)d_out;

  char* ws = (char*)d_ws;
  const size_t SZY  = (size_t)4096 * 1024 * 2;        // 8,388,608
  const size_t SZW  = (size_t)3072 * 1024 * 2;        // 6,291,456
  const size_t SZW2 = (size_t)2048 * 1024 * 2;        // 4,194,304
  const size_t SZQ  = (size_t)2 * 16 * 2048 * 64 * 4; // 16,777,216 (fp32)
  const size_t SZK  = (size_t)2 * 16 * 2048 * 64 * 2; //  8,388,608 (bf16)

  unsigned short* y0 = (unsigned short*)(ws);
  unsigned short* y1 = (unsigned short*)(ws + SZY);
  unsigned short* y2 = (unsigned short*)(ws + 2 * SZY);
  unsigned short* W0 = (unsigned short*)(ws + 3 * SZY);
  unsigned short* W1 = (unsigned short*)(ws + 3 * SZY + SZW);
  unsigned short* W2 = (unsigned short*)(ws + 3 * SZY + 2 * SZW);
  float* Qf          = (float*)(ws + 3 * SZY + 2 * SZW + SZW2);
  unsigned short* K0 = (unsigned short*)(ws + 3 * SZY + 2 * SZW + SZW2 + SZQ);
  unsigned short* K1 = (unsigned short*)(ws + 3 * SZY + 2 * SZW + SZW2 + SZQ + SZK);
  float* E           = (float*)(ws + 3 * SZY + 2 * SZW + SZW2 + SZQ + 2 * SZK);
  float* Einv        = E + T_SEQ;
  // aliases into dead regions (y dead after qkv_*, then reused):
  unsigned short* Ob0 = y0;
  unsigned short* Ob1 = y1;
  unsigned short* PW0 = y2;
  unsigned short* PW1 = y2 + (size_t)1024 * 1024;
  // d_out scratch (16.78 MB): VbT low half, K2 high half; both dead before proj writes
  unsigned short* VbT = (unsigned short*)d_out;
  unsigned short* K2  = (unsigned short*)((char*)d_out + SZK);

  size_t needed = 3 * SZY + 2 * SZW + SZW2 + SZQ + 2 * SZK + 2 * T_SEQ * 4;  // 75,513,856
  if (ws_size < needed) return;  // loud failure: output stays zero

  eta_kernel<<<dim3(8), dim3(256), 0, stream>>>(theta, E, Einv);
  ln_kernel<<<dim3(4096), dim3(256), 0, stream>>>(x, ln_w, y0, y1, y2);
  conv_w3<<<dim3(1536), dim3(256), 0, stream>>>(attn_w, W0, W1, W2);
  qkv_qk<<<dim3(16, 32), dim3(256), 0, stream>>>(y0, y1, y2, W0, W1, W2, Qf, K0, K1, K2);
  qkv_v<<<dim3(8, 32), dim3(256), 0, stream>>>(y0, y1, W0, W1, VbT);
  attn_kernel<<<dim3(16, 32), dim3(256), 0, stream>>>(Qf, K0, K1, K2, VbT, E, Einv, Ob0, Ob1);
  conv_pw<<<dim3(512), dim3(256), 0, stream>>>(proj_w, PW0, PW1);
  proj_gemm<<<dim3(8, 32), dim3(256), 0, stream>>>(Ob0, Ob1, PW0, PW1, out);
}